// Round 19
// baseline (267.482 us; speedup 1.0000x reference)
//
#include <hip/hip_runtime.h>

// CausalSelfAttention: B=2,S=2048,H=2048,NH=16,NKV=4,HD=128, fp32 in/out,
// internal bf16 MFMA pipeline.
// Round 19 = Round 18 + K-MAJOR LDS layout in the GEMM:
// r18 proved the 6.29M bank conflicts are the K-loop ds_read_b128s (epilogue
// stride change left the count bit-identical). Row-major [row][32k] makes
// rows 2 apart alias (64B rows); fragment reads were 4-way conflicted.
// New layout [j=k-chunk][row][8elems]: fragment read = (j*128+row)*16B ->
// banks (row*4)%32, conflict-free in consecutive-8-lane groups. Staging
// keeps LINEAR LDS dest (global_load_lds rule) with PER-LANE global sources:
// lane l stages row i*64+l of k-chunk w (src = T + row*K + k0 + w*8).
// attn = r14 structure verbatim (81us). Epilogue/prep unchanged.
// ws layout (bytes), total 62,914,560:
//   [0,16.8M)          xb (live: prep+QKV GEMM) -> later Yb
//   [16.8M,29.36M)     WqkvT bf16 [3072][2048] (live: QKV GEMM)
//   [29.36M,37.75M)    WoT bf16 [2048][2048]   (live: until out GEMM)
//   [37.75M,54.53M)    Qpk (16MB)   [54.53M,58.72M) Kpk   [58.72M,62.91M) Vpk

#define S_LEN 2048

typedef __bf16 bf16_t;
typedef bf16_t bf16x8 __attribute__((ext_vector_type(8)));
typedef float f32x4 __attribute__((ext_vector_type(4)));
typedef float f32x16 __attribute__((ext_vector_type(16)));
typedef unsigned int u32x4 __attribute__((ext_vector_type(4)));
typedef unsigned short u16x4 __attribute__((ext_vector_type(4)));

__device__ __forceinline__ unsigned short f2bf(float f) {
  unsigned int u = __builtin_bit_cast(unsigned int, f);
  u += 0x7fffu + ((u >> 16) & 1u);
  return (unsigned short)(u >> 16);
}
__device__ __forceinline__ float bf2f(unsigned short h) {
  return __builtin_bit_cast(float, (unsigned int)h << 16);
}
__device__ __forceinline__ unsigned pk2(float a, float b) {
  return (unsigned)f2bf(a) | ((unsigned)f2bf(b) << 16);
}
// HW packed convert: lo = bf16(a), hi = bf16(b). Single VALU instruction.
__device__ __forceinline__ unsigned cvtpk(float a, float b) {
  unsigned r;
  asm("v_cvt_pk_bf16_f32 %0, %1, %2" : "=v"(r) : "v"(a), "v"(b));
  return r;
}

typedef const __attribute__((address_space(1))) unsigned int* gas1_t;
typedef __attribute__((address_space(3))) unsigned int* las3_t;
__device__ __forceinline__ void async16(const void* g, void* l) {
  __builtin_amdgcn_global_load_lds((gas1_t)g, (las3_t)l, 16, 0, 0);
}

__device__ __forceinline__ bf16x8 ldfrag(const void* p) {
  return __builtin_bit_cast(bf16x8, *(const u32x4*)p);
}
__device__ __forceinline__ f32x16 mfma32(bf16x8 a, bf16x8 b, f32x16 c) {
  return __builtin_amdgcn_mfma_f32_32x32x16_bf16(a, b, c, 0, 0, 0);
}
__device__ __forceinline__ f32x16 zero16() {
  f32x16 v;
#pragma unroll
  for (int i = 0; i < 16; i++) v[i] = 0.f;
  return v;
}

// ---------------- fused prep: cast x + 4 weight transposes ----------------
__device__ __forceinline__ void transpose_body(
    const float* __restrict__ in, unsigned short* __restrict__ out,
    int C, int out_row_off, int out_ld, int bx, int by, int t,
    unsigned short (*L)[68]) {
  int r0 = by * 64, c0 = bx * 64;
#pragma unroll
  for (int i = 0; i < 4; i++) {
    int r = i * 16 + (t >> 4);
    int c = (t & 15) * 4;
    f32x4 v = *(const f32x4*)&in[(size_t)(r0 + r) * C + c0 + c];
    u16x4 u;
    u.x = f2bf(v.x); u.y = f2bf(v.y); u.z = f2bf(v.z); u.w = f2bf(v.w);
    *(u16x4*)&L[r][c] = u;
  }
  __syncthreads();
#pragma unroll
  for (int i = 0; i < 4; i++) {
    int oc = i * 16 + (t >> 4);
    int orr = (t & 15) * 4;
    u16x4 u;
    u.x = L[orr + 0][oc]; u.y = L[orr + 1][oc];
    u.z = L[orr + 2][oc]; u.w = L[orr + 3][oc];
    *(u16x4*)&out[(size_t)(c0 + oc + out_row_off) * out_ld + r0 + orr] = u;
  }
}

__global__ __launch_bounds__(256) void prep_kernel(
    const float* __restrict__ x, const float* __restrict__ Wq,
    const float* __restrict__ Wk, const float* __restrict__ Wv,
    const float* __restrict__ Wo, unsigned short* __restrict__ xb,
    unsigned short* __restrict__ WT, unsigned short* __restrict__ WoT) {
  __shared__ unsigned short L[64][68];
  const int bid = blockIdx.x, t = threadIdx.x;
  if (bid < 4096) {                       // cast x: 1048576 x 8 elems
    int i = bid * 256 + t;
    const f32x4* p = (const f32x4*)x + (size_t)i * 2;
    f32x4 a = p[0], b = p[1];
    u32x4 o;
    o.x = pk2(a.x, a.y);
    o.y = pk2(a.z, a.w);
    o.z = pk2(b.x, b.y);
    o.w = pk2(b.z, b.w);
    *(u32x4*)(xb + (size_t)i * 8) = o;
  } else if (bid < 5120) {                // Wq^T -> WT rows [0,2048)
    int id = bid - 4096;
    transpose_body(Wq, WT, 2048, 0, 2048, id & 31, id >> 5, t, L);
  } else if (bid < 5376) {                // Wk^T -> WT rows [2048,2560)
    int id = bid - 5120;
    transpose_body(Wk, WT, 512, 2048, 2048, id & 7, id >> 3, t, L);
  } else if (bid < 5632) {                // Wv^T -> WT rows [2560,3072)
    int id = bid - 5376;
    transpose_body(Wv, WT, 512, 2560, 2048, id & 7, id >> 3, t, L);
  } else {                                // Wo^T -> WoT
    int id = bid - 5632;
    transpose_body(Wo, WoT, 2048, 0, 2048, id & 31, id >> 5, t, L);
  }
}

// ---------------- bf16 GEMM (+ optional fused mid epilogue) ----------------
// C[M][N] = A[M][K]*Bt[N][K]^T. 128x128 tile, BK=32. Triple-buffered LDS
// in K-MAJOR layout [j][row][8] (conflict-free ds_read_b128), 2 tiles in
// flight, counted vmcnt(8). If Qpk!=nullptr (QKV GEMM): col-tile bx == head;
// epilogue dumps acc into a [128][132] LDS tile overlaying dead staging,
// then runs RMSNorm+RoPE+fragment-packing per row.
__global__ __launch_bounds__(256) void gemm_bf16_kernel(
    const unsigned short* __restrict__ A, const unsigned short* __restrict__ Bt,
    void* __restrict__ Cout, int M, int N, int K, int out_bf16,
    const float* __restrict__ cosT, const float* __restrict__ sinT,
    const float* __restrict__ qw, const float* __restrict__ kw,
    unsigned short* __restrict__ Qpk, unsigned short* __restrict__ Kpk,
    unsigned short* __restrict__ Vpk) {
  __shared__ __attribute__((aligned(16))) unsigned short shbuf[24576];  // 49152 B
  unsigned short* As = shbuf;            // 3 x [4 j][128 row][8] (24KB)
  unsigned short* Bs = shbuf + 12288;    // 3 x [4 j][128 row][8] (24KB)
  const int t = threadIdx.x, w = t >> 6, l = t & 63;
  const int wr = w >> 1, wc = w & 1;
  const int lrow = l & 15, lhi = l >> 4;
  const int row0 = blockIdx.y * 128, col0 = blockIdx.x * 128;
  const unsigned short* Ab = A + (size_t)row0 * K;
  const unsigned short* Bb = Bt + (size_t)col0 * K;
  f32x4 z = {0.f, 0.f, 0.f, 0.f};
  f32x4 acc[4][4];
#pragma unroll
  for (int m = 0; m < 4; m++)
#pragma unroll
    for (int n = 0; n < 4; n++) acc[m][n] = z;

  // K-major staging: wave w stages k-chunk j=w for rows 0-63 (i=0) and
  // 64-127 (i=1). LDS dest is linear in lane (base + l*16B); global source
  // is per-lane row-strided (allowed: only the DEST must be linear).
#define STAGE_G(tt, buf)                                                        \
  {                                                                             \
    const int k0_ = (tt) * 32;                                                  \
    async16(Ab + (size_t)l * K + k0_ + w * 8,        &As[(buf) * 4096 + (w * 128 + l) * 8]); \
    async16(Ab + (size_t)(64 + l) * K + k0_ + w * 8, &As[(buf) * 4096 + (w * 128 + 64 + l) * 8]); \
    async16(Bb + (size_t)l * K + k0_ + w * 8,        &Bs[(buf) * 4096 + (w * 128 + l) * 8]); \
    async16(Bb + (size_t)(64 + l) * K + k0_ + w * 8, &Bs[(buf) * 4096 + (w * 128 + 64 + l) * 8]); \
  }

  const int NT = K >> 5;                 // 64 for both GEMMs
  STAGE_G(0, 0);
  STAGE_G(1, 1);
  for (int tt = 0; tt < NT; tt++) {
    const int cur = tt % 3;
    if (tt + 2 < NT) {
      STAGE_G(tt + 2, (tt + 2) % 3);
      asm volatile("s_waitcnt vmcnt(8)" ::: "memory");   // tile tt landed; tt+1,tt+2 in flight
    } else if (tt + 1 < NT) {
      asm volatile("s_waitcnt vmcnt(4)" ::: "memory");   // tile tt landed; tt+1 in flight
    } else {
      asm volatile("s_waitcnt vmcnt(0)" ::: "memory");
    }
    __builtin_amdgcn_s_barrier();
    __builtin_amdgcn_sched_barrier(0);
    bf16x8 af[4], bfr[4];
#pragma unroll
    for (int m = 0; m < 4; m++)
      af[m] = ldfrag(&As[cur * 4096 + (lhi * 128 + wr * 64 + m * 16 + lrow) * 8]);
#pragma unroll
    for (int n = 0; n < 4; n++)
      bfr[n] = ldfrag(&Bs[cur * 4096 + (lhi * 128 + wc * 64 + n * 16 + lrow) * 8]);
    __builtin_amdgcn_s_setprio(1);
#pragma unroll
    for (int m = 0; m < 4; m++)
#pragma unroll
      for (int n = 0; n < 4; n++)
        acc[m][n] = __builtin_amdgcn_mfma_f32_16x16x32_bf16(af[m], bfr[n], acc[m][n], 0, 0, 0);
    __builtin_amdgcn_s_setprio(0);
    __builtin_amdgcn_sched_barrier(0);
    __builtin_amdgcn_s_barrier();   // all waves done reading buf cur before it is restaged
  }
#undef STAGE_G

  if (Qpk) {
    // ---------- fused mid epilogue ----------
    // acc -> LDS tile [128][132] bf16 (overlays dead staging)
#pragma unroll
    for (int m = 0; m < 4; m++)
#pragma unroll
      for (int n = 0; n < 4; n++)
#pragma unroll
        for (int r = 0; r < 4; r++)
          shbuf[(wr * 64 + m * 16 + lhi * 4 + r) * 132 + wc * 64 + n * 16 + lrow] =
              f2bf(acc[m][n][r]);
    __syncthreads();
    const int head = blockIdx.x;           // col-tile == head
    const int d0 = 2 * l;
    for (int rr = 0; rr < 32; rr++) {
      const int row = w * 32 + rr;
      const int bs = row0 + row;
      const int b = bs >> 11, s = bs & 2047;
      unsigned int uu = *(const unsigned int*)&shbuf[row * 132 + d0];
      float x0 = bf2f((unsigned short)(uu & 0xffffu));
      float x1 = bf2f((unsigned short)(uu >> 16));
      if (head < 20) {
        const float* nw = (head < 16) ? qw : kw;
        float ss = x0 * x0 + x1 * x1;
#pragma unroll
        for (int mk = 1; mk < 64; mk <<= 1) ss += __shfl_xor(ss, mk);
        float inv = rsqrtf(ss * (1.0f / 128.0f) + 1e-6f);
        float n0 = x0 * inv * nw[d0], n1 = x1 * inv * nw[d0 + 1];
        float p0 = __shfl_xor(n0, 32), p1 = __shfl_xor(n1, 32);
        float sg = (l < 32) ? -1.0f : 1.0f;
        float c0 = cosT[s * 128 + d0], c1 = cosT[s * 128 + d0 + 1];
        float sn0 = sinT[s * 128 + d0], sn1 = sinT[s * 128 + d0 + 1];
        float o0 = n0 * c0 + sg * p0 * sn0;
        float o1 = n1 * c1 + sg * p1 * sn1;
        int mf = d0 >> 4, hi = (d0 >> 3) & 1, j = d0 & 7;
        int blk = s >> 5, r31 = s & 31;
        int foff = (mf * 2 + hi) * 256 + r31 * 8 + j;
        unsigned short* dst;
        if (head < 16) {
          const float qs = 0.08838834764831845f * 1.4426950408889634f;  // 1/sqrt(128)*log2e
          o0 *= qs; o1 *= qs;
          dst = Qpk + (((size_t)(b * 16 + head)) * 64 + blk) * 4096 + foff;
        } else {
          dst = Kpk + (((size_t)(b * 4 + (head - 16))) * 64 + blk) * 4096 + foff;
        }
        *(unsigned int*)dst = pk2(o0, o1);
      } else {
        int kvh = head - 20;
        int blk = s >> 5, ks = (s >> 4) & 1, his = (s >> 3) & 1, j = s & 7;
        int n = d0 >> 5, d31 = d0 & 31;
        size_t base = (((size_t)(b * 4 + kvh)) * 64 + blk) * 4096 +
                      (((n * 2 + ks) * 2 + his) * 256 + d31 * 8 + j);
        Vpk[base] = f2bf(x0);
        Vpk[base + 8] = f2bf(x1);   // d0+1 -> d31+1
      }
    }
  } else if (out_bf16) {
    unsigned short* C = (unsigned short*)Cout;
#pragma unroll
    for (int m = 0; m < 4; m++)
#pragma unroll
      for (int n = 0; n < 4; n++)
#pragma unroll
        for (int r = 0; r < 4; r++) {
          size_t grow = row0 + wr * 64 + m * 16 + lhi * 4 + r;
          size_t gcol = col0 + wc * 64 + n * 16 + lrow;
          C[grow * N + gcol] = f2bf(acc[m][n][r]);
        }
  } else {
    float* C = (float*)Cout;
#pragma unroll
    for (int m = 0; m < 4; m++)
#pragma unroll
      for (int n = 0; n < 4; n++)
#pragma unroll
        for (int r = 0; r < 4; r++) {
          size_t grow = row0 + wr * 64 + m * 16 + lhi * 4 + r;
          size_t gcol = col0 + wc * 64 + n * 16 + lrow;
          C[grow * N + gcol] = acc[m][n][r];
        }
  }
}

// ---------------- flash attention: 8-wave KV-split, triple-buf, 1 barrier/round ----
// (r14 structure, verbatim.) 256 blocks x 8 waves (512 thr). bid&7 -> (b,kvh)
// (XCD-pinned K/V); pj=bid>>3: block runs strip 63-pj then strip pj (33-34
// rounds each, equal). Waves: grp = w>>2 (KV-half), hw = w&3 (head). Private
// online softmax per group; 2-way in-LDS flash combine at strip end (cold
// path, __syncthreads). Staging: 3 bufs x 2 grps x 16KB, one s_barrier per
// round. Softmax fmax/sum as trees.
// LDS: [0,98304) staging; epilogue obuf overlays dead staging; mlb at
// [98304,100352).
__global__ __launch_bounds__(512) void attn_kernel(
    const unsigned short* __restrict__ Qpk, const unsigned short* __restrict__ Kpk,
    const unsigned short* __restrict__ Vpk, unsigned short* __restrict__ Y) {
  __shared__ __attribute__((aligned(16))) unsigned char lds_raw[100352];
  const int t = threadIdx.x, w = t >> 6, l = t & 63;
  const int q31 = l & 31, hi = l >> 5;
  const int grp = w >> 2, hw = w & 3;
  const int bid = blockIdx.x;
  const int xcd = bid & 7;
  const int b = xcd >> 2, kvh = xcd & 3;
  const int hd = kvh * 4 + hw;
  const int bh = b * 16 + hd;
  const int pj = bid >> 3;
  const unsigned short* Kg = Kpk + (size_t)(b * 4 + kvh) * 262144;
  const unsigned short* Vg = Vpk + (size_t)(b * 4 + kvh) * 262144;
  float* mlb = (float*)(lds_raw + 98304);   // [head][grp][{m,l}][q31], 2KB

#define STAGE1(st, buf)                                                        \
  {                                                                            \
    unsigned char* base_ = lds_raw + ((buf) * 2 + grp) * 16384;                \
    const unsigned short* kg_ = Kg + (size_t)(st) * 4096;                      \
    const unsigned short* vg_ = Vg + (size_t)(st) * 4096;                      \
    _Pragma("unroll")                                                          \
    for (int i_ = 0; i_ < 4; i_++) {                                           \
      int c_ = hw * 4 + i_;                                                    \
      const unsigned short* src_ = (c_ < 8) ? (kg_ + c_ * 512 + l * 8)         \
                                            : (vg_ + (c_ - 8) * 512 + l * 8);  \
      async16(src_, base_ + c_ * 1024 + l * 16);                               \
    }                                                                          \
  }

  for (int phase = 0; phase < 2; phase++) {
    const int strip = phase ? pj : (63 - pj);
    const int q0w = strip * 32;
    const int qg = q0w + q31;
    const int nt = strip + 1;
    const int hcut = (nt + 1) >> 1;
    const int myFirst = grp ? hcut : 0;
    const int myCnt = grp ? (nt - hcut) : hcut;
    const int R = hcut;

    const unsigned short* Qs = Qpk + (((size_t)bh * 64 + strip) * 4096) + (size_t)l * 8;
    bf16x8 qf[8];
#pragma unroll
    for (int mf = 0; mf < 8; mf++) qf[mf] = ldfrag(Qs + mf * 512);
    asm volatile("s_waitcnt vmcnt(0)" ::: "memory");  // Q resolved; vmcnt exact

    { int st0 = (myCnt > 0) ? myFirst : 0; STAGE1(st0, 0); }

    f32x16 o[4];
#pragma unroll
    for (int n = 0; n < 4; n++) o[n] = zero16();
    float m = -3.0e38f, lsum = 0.f;

    for (int r = 0; r < R; r++) {
      const int buf = r % 3;
      { int st = (r + 1 < myCnt) ? (myFirst + r + 1) : 0; STAGE1(st, (r + 1) % 3); }
      asm volatile("s_waitcnt vmcnt(4)" ::: "memory");  // my round-r stage landed
      __builtin_amdgcn_s_barrier();
      __builtin_amdgcn_sched_barrier(0);

      if (r < myCnt) {
        const int ti = myFirst + r;
        const int kv0 = ti << 5;
        const unsigned short* base =
            (const unsigned short*)(lds_raw + (buf * 2 + grp) * 16384);
        // ---- QK^T (swapped): two 4-deep chains, then merge ----
        f32x16 sA = zero16(), sB = zero16();
        __builtin_amdgcn_s_setprio(1);
#pragma unroll
        for (int mf = 0; mf < 4; mf++) {
          sA = mfma32(ldfrag(base + mf * 512 + l * 8), qf[mf], sA);
          sB = mfma32(ldfrag(base + (mf + 4) * 512 + l * 8), qf[mf + 4], sB);
        }
        __builtin_amdgcn_s_setprio(0);
#pragma unroll
        for (int rr = 0; rr < 16; rr++) sA[rr] += sB[rr];
        // ---- causal mask (diagonal tile only; tile nt-1 has kv0 == q0w) ----
        if (ti == nt - 1) {
#pragma unroll
          for (int rr = 0; rr < 16; rr++) {
            int kv = kv0 + (rr & 3) + 8 * (rr >> 2) + 4 * hi;
            if (kv > qg) sA[rr] = -3.0e38f;
          }
        }
        // ---- online softmax (lane-local row, exp2 units), TREE reductions ----
        float a0 = fmaxf(sA[0], sA[1]),   a1 = fmaxf(sA[2], sA[3]);
        float a2 = fmaxf(sA[4], sA[5]),   a3 = fmaxf(sA[6], sA[7]);
        float a4 = fmaxf(sA[8], sA[9]),   a5 = fmaxf(sA[10], sA[11]);
        float a6 = fmaxf(sA[12], sA[13]), a7 = fmaxf(sA[14], sA[15]);
        a0 = fmaxf(fmaxf(a0, a1), a2);    // v_max3-fusable
        a3 = fmaxf(fmaxf(a3, a4), a5);
        a6 = fmaxf(a6, a7);
        float pm = fmaxf(fmaxf(a0, a3), a6);
        pm = fmaxf(pm, __shfl_xor(pm, 32));
        if (__any(pm > m + 8.0f)) {   // defer-max
          float mn = fmaxf(m, pm);
          float scl = exp2f(m - mn);
          m = mn; lsum *= scl;
#pragma unroll
          for (int rr = 0; rr < 16; rr++) {
            float sr = __shfl(scl, (rr & 3) + 8 * (rr >> 2) + 4 * hi);
            o[0][rr] *= sr; o[1][rr] *= sr; o[2][rr] *= sr; o[3][rr] *= sr;
          }
        }
#pragma unroll
        for (int rr = 0; rr < 16; rr++) sA[rr] = exp2f(sA[rr] - m);
        float s0 = (sA[0] + sA[1]) + (sA[2] + sA[3]);
        float s1 = (sA[4] + sA[5]) + (sA[6] + sA[7]);
        float s2 = (sA[8] + sA[9]) + (sA[10] + sA[11]);
        float s3 = (sA[12] + sA[13]) + (sA[14] + sA[15]);
        float ts = (s0 + s1) + (s2 + s3);
        ts += __shfl_xor(ts, 32);
        lsum += ts;
        // ---- pack P -> A-operand fragments (register exchange) ----
        bf16x8 paf[2];
#pragma unroll
        for (int f = 0; f < 2; f++) {
          const int bs8 = 8 * f;
          unsigned g00 = cvtpk(sA[bs8 + 0], sA[bs8 + 1]);
          unsigned g01 = cvtpk(sA[bs8 + 2], sA[bs8 + 3]);
          unsigned g10 = cvtpk(sA[bs8 + 4], sA[bs8 + 5]);
          unsigned g11 = cvtpk(sA[bs8 + 6], sA[bs8 + 7]);
          unsigned snd0 = hi ? g00 : g10;
          unsigned snd1 = hi ? g01 : g11;
          unsigned r0 = (unsigned)__shfl_xor((int)snd0, 32);
          unsigned r1 = (unsigned)__shfl_xor((int)snd1, 32);
          unsigned own0 = hi ? g10 : g00;
          unsigned own1 = hi ? g11 : g01;
          u32x4 wv;
          wv.x = hi ? r0 : own0;
          wv.y = hi ? r1 : own1;
          wv.z = hi ? own0 : r0;
          wv.w = hi ? own1 : r1;
          paf[f] = __builtin_bit_cast(bf16x8, wv);
        }
        // ---- PV ----
        __builtin_amdgcn_s_setprio(1);
#pragma unroll
        for (int n = 0; n < 4; n++) {
          o[n] = mfma32(paf[0], ldfrag(base + 4096 + (n * 2 + 0) * 512 + l * 8), o[n]);
          o[n] = mfma32(paf[1], ldfrag(base + 4096 + (n * 2 + 1) * 512 + l * 8), o[n]);
        }
        __builtin_amdgcn_s_setprio(0);
      }
      // no second barrier: triple buffer makes the restage safe
    }

    // ---- combine the two KV-half partials (in LDS; cold path, full syncs) ----
    __syncthreads();
    if (l < 32) {
      mlb[hw * 128 + grp * 64 + q31] = m;
      mlb[hw * 128 + grp * 64 + 32 + q31] = lsum;
    }
    __syncthreads();
    float m_o = mlb[hw * 128 + (grp ^ 1) * 64 + q31];
    float l_o = mlb[hw * 128 + (grp ^ 1) * 64 + 32 + q31];
    float M = fmaxf(m, m_o);
    float sc = exp2f(m - M);
    float lF = lsum * sc + l_o * exp2f(m_o - M);
#pragma unroll
    for (int rr = 0; rr < 16; rr++) {
      float sr = __shfl(sc, (rr & 3) + 8 * (rr >> 2) + 4 * hi);
      o[0][rr] *= sr; o[1][rr] *= sr; o[2][rr] *= sr; o[3][rr] *= sr;
    }
    float* ob = (float*)lds_raw + hw * 4096;   // [q32][d128] per head (staging dead now)
    if (grp == 1) {
#pragma unroll
      for (int rr = 0; rr < 16; rr++) {
        int cr = (rr & 3) + 8 * (rr >> 2) + 4 * hi;
#pragma unroll
        for (int n = 0; n < 4; n++) ob[cr * 128 + n * 32 + q31] = o[n][rr];
      }
    }
    __syncthreads();
    if (grp == 0) {
      float linv = 1.0f / lF;
#pragma unroll
      for (int rr = 0; rr < 16; rr++) {
        int cr = (rr & 3) + 8 * (rr >> 2) + 4 * hi;
        float lr = __shfl(linv, cr);
        int qrow = q0w + cr;
        size_t rowoff = ((size_t)(b * S_LEN + qrow)) * 2048 + hd * 128 + q31;
        Y[rowoff]      = f2bf((o[0][rr] + ob[cr * 128 + q31]) * lr);
        Y[rowoff + 32] = f2bf((o[1][rr] + ob[cr * 128 + 32 + q31]) * lr);
        Y[rowoff + 64] = f2bf((o[2][rr] + ob[cr * 128 + 64 + q31]) * lr);
        Y[rowoff + 96] = f2bf((o[3][rr] + ob[cr * 128 + 96 + q31]) * lr);
      }
    }
    __syncthreads();   // obuf consumed before next phase restages
  }
#undef STAGE1
}

// ---------------- launch ----------------
extern "C" void kernel_launch(void* const* d_in, const int* in_sizes, int n_in,
                              void* d_out, int out_size, void* d_ws, size_t ws_size,
                              hipStream_t stream) {
  const float* x  = (const float*)d_in[0];
  const float* rc = (const float*)d_in[1];
  const float* rs = (const float*)d_in[2];
  const float* Wq = (const float*)d_in[3];
  const float* Wk = (const float*)d_in[4];
  const float* Wv = (const float*)d_in[5];
  const float* Wo = (const float*)d_in[6];
  const float* qw = (const float*)d_in[7];
  const float* kw = (const float*)d_in[8];
  float* out = (float*)d_out;
  char* ws = (char*)d_ws;

  unsigned short* xb   = (unsigned short*)(ws + 0);          // live: prep + QKV GEMM
  unsigned short* WT   = (unsigned short*)(ws + 16777216);   // live: QKV GEMM
  unsigned short* WoT  = (unsigned short*)(ws + 29360128);   // live: until out GEMM
  unsigned short* Qpk  = (unsigned short*)(ws + 37748736);   // 16MB
  unsigned short* Kpk  = (unsigned short*)(ws + 54525952);   // 4MB
  unsigned short* Vpk  = (unsigned short*)(ws + 58720256);   // 4MB
  unsigned short* Yb   = (unsigned short*)(ws + 0);          // over xb (dead after QKV GEMM)

  prep_kernel<<<6656, 256, 0, stream>>>(x, Wq, Wk, Wv, Wo, xb, WT, WoT);
  gemm_bf16_kernel<<<dim3(24, 32), 256, 0, stream>>>(
      xb, WT, nullptr, 4096, 3072, 2048, 1, rc, rs, qw, kw, Qpk, Kpk, Vpk);
  attn_kernel<<<256, 512, 0, stream>>>(Qpk, Kpk, Vpk, Yb);
  gemm_bf16_kernel<<<dim3(16, 32), 256, 0, stream>>>(
      Yb, WoT, out, 4096, 2048, 2048, 0, nullptr, nullptr, nullptr, nullptr,
      nullptr, nullptr, nullptr);
}

// Round 20
// 212.445 us; speedup vs baseline: 1.2591x; 1.2591x over previous
//
#include <hip/hip_runtime.h>

// CausalSelfAttention: B=2,S=2048,H=2048,NH=16,NKV=4,HD=128, fp32 in/out,
// internal bf16 MFMA pipeline.
// Round 20: GEMM K-loop -> ONE barrier per round (attn-proven triple-buffer
// discipline). r18/r19 pair proved LDS bank conflicts are NOT critical-path
// (removing them entirely made things worse via staging gather); the 2-phase
// overhead (stage+vmcnt+2 barriers per K-step) is. Staging reverted to r18
// row-major (coalesced). Loop: { STAGE(tt+1 -> (tt+1)%3); vmcnt(4); barrier;
// read tt%3; MFMA }. Safety: between barriers r-1 and r waves touch only
// bufs (r-1)%3 and r%3; staging targets (r+1)%3 -- disjoint (mod 3).
// Extra __syncthreads() before the fused epilogue's LDS-overlay reuse.
// attn = r14 structure verbatim (81us).
// ws layout (bytes), total 62,914,560:
//   [0,16.8M)          xb (live: prep+QKV GEMM) -> later Yb
//   [16.8M,29.36M)     WqkvT bf16 [3072][2048] (live: QKV GEMM)
//   [29.36M,37.75M)    WoT bf16 [2048][2048]   (live: until out GEMM)
//   [37.75M,54.53M)    Qpk (16MB)   [54.53M,58.72M) Kpk   [58.72M,62.91M) Vpk

#define S_LEN 2048

typedef __bf16 bf16_t;
typedef bf16_t bf16x8 __attribute__((ext_vector_type(8)));
typedef float f32x4 __attribute__((ext_vector_type(4)));
typedef float f32x16 __attribute__((ext_vector_type(16)));
typedef unsigned int u32x4 __attribute__((ext_vector_type(4)));
typedef unsigned short u16x4 __attribute__((ext_vector_type(4)));

__device__ __forceinline__ unsigned short f2bf(float f) {
  unsigned int u = __builtin_bit_cast(unsigned int, f);
  u += 0x7fffu + ((u >> 16) & 1u);
  return (unsigned short)(u >> 16);
}
__device__ __forceinline__ float bf2f(unsigned short h) {
  return __builtin_bit_cast(float, (unsigned int)h << 16);
}
__device__ __forceinline__ unsigned pk2(float a, float b) {
  return (unsigned)f2bf(a) | ((unsigned)f2bf(b) << 16);
}
// HW packed convert: lo = bf16(a), hi = bf16(b). Single VALU instruction.
__device__ __forceinline__ unsigned cvtpk(float a, float b) {
  unsigned r;
  asm("v_cvt_pk_bf16_f32 %0, %1, %2" : "=v"(r) : "v"(a), "v"(b));
  return r;
}

typedef const __attribute__((address_space(1))) unsigned int* gas1_t;
typedef __attribute__((address_space(3))) unsigned int* las3_t;
__device__ __forceinline__ void async16(const void* g, void* l) {
  __builtin_amdgcn_global_load_lds((gas1_t)g, (las3_t)l, 16, 0, 0);
}

__device__ __forceinline__ bf16x8 ldfrag(const void* p) {
  return __builtin_bit_cast(bf16x8, *(const u32x4*)p);
}
__device__ __forceinline__ f32x16 mfma32(bf16x8 a, bf16x8 b, f32x16 c) {
  return __builtin_amdgcn_mfma_f32_32x32x16_bf16(a, b, c, 0, 0, 0);
}
__device__ __forceinline__ f32x16 zero16() {
  f32x16 v;
#pragma unroll
  for (int i = 0; i < 16; i++) v[i] = 0.f;
  return v;
}

// ---------------- fused prep: cast x + 4 weight transposes ----------------
__device__ __forceinline__ void transpose_body(
    const float* __restrict__ in, unsigned short* __restrict__ out,
    int C, int out_row_off, int out_ld, int bx, int by, int t,
    unsigned short (*L)[68]) {
  int r0 = by * 64, c0 = bx * 64;
#pragma unroll
  for (int i = 0; i < 4; i++) {
    int r = i * 16 + (t >> 4);
    int c = (t & 15) * 4;
    f32x4 v = *(const f32x4*)&in[(size_t)(r0 + r) * C + c0 + c];
    u16x4 u;
    u.x = f2bf(v.x); u.y = f2bf(v.y); u.z = f2bf(v.z); u.w = f2bf(v.w);
    *(u16x4*)&L[r][c] = u;
  }
  __syncthreads();
#pragma unroll
  for (int i = 0; i < 4; i++) {
    int oc = i * 16 + (t >> 4);
    int orr = (t & 15) * 4;
    u16x4 u;
    u.x = L[orr + 0][oc]; u.y = L[orr + 1][oc];
    u.z = L[orr + 2][oc]; u.w = L[orr + 3][oc];
    *(u16x4*)&out[(size_t)(c0 + oc + out_row_off) * out_ld + r0 + orr] = u;
  }
}

__global__ __launch_bounds__(256) void prep_kernel(
    const float* __restrict__ x, const float* __restrict__ Wq,
    const float* __restrict__ Wk, const float* __restrict__ Wv,
    const float* __restrict__ Wo, unsigned short* __restrict__ xb,
    unsigned short* __restrict__ WT, unsigned short* __restrict__ WoT) {
  __shared__ unsigned short L[64][68];
  const int bid = blockIdx.x, t = threadIdx.x;
  if (bid < 4096) {                       // cast x: 1048576 x 8 elems
    int i = bid * 256 + t;
    const f32x4* p = (const f32x4*)x + (size_t)i * 2;
    f32x4 a = p[0], b = p[1];
    u32x4 o;
    o.x = pk2(a.x, a.y);
    o.y = pk2(a.z, a.w);
    o.z = pk2(b.x, b.y);
    o.w = pk2(b.z, b.w);
    *(u32x4*)(xb + (size_t)i * 8) = o;
  } else if (bid < 5120) {                // Wq^T -> WT rows [0,2048)
    int id = bid - 4096;
    transpose_body(Wq, WT, 2048, 0, 2048, id & 31, id >> 5, t, L);
  } else if (bid < 5376) {                // Wk^T -> WT rows [2048,2560)
    int id = bid - 5120;
    transpose_body(Wk, WT, 512, 2048, 2048, id & 7, id >> 3, t, L);
  } else if (bid < 5632) {                // Wv^T -> WT rows [2560,3072)
    int id = bid - 5376;
    transpose_body(Wv, WT, 512, 2560, 2048, id & 7, id >> 3, t, L);
  } else {                                // Wo^T -> WoT
    int id = bid - 5632;
    transpose_body(Wo, WoT, 2048, 0, 2048, id & 31, id >> 5, t, L);
  }
}

// ---------------- bf16 GEMM (+ optional fused mid epilogue) ----------------
// C[M][N] = A[M][K]*Bt[N][K]^T. 128x128 tile, BK=32, row-major LDS staging
// (r18), triple-buffered with ONE s_barrier per K-round (stage tt+1 ->
// (tt+1)%3 pre-barrier; compute tt%3 post-barrier). If Qpk!=nullptr (QKV
// GEMM): col-tile bx == head; epilogue (after a full __syncthreads) dumps
// acc into a [128][132] LDS tile overlaying staging, then runs RMSNorm+
// RoPE+fragment-packing per row.
__global__ __launch_bounds__(256) void gemm_bf16_kernel(
    const unsigned short* __restrict__ A, const unsigned short* __restrict__ Bt,
    void* __restrict__ Cout, int M, int N, int K, int out_bf16,
    const float* __restrict__ cosT, const float* __restrict__ sinT,
    const float* __restrict__ qw, const float* __restrict__ kw,
    unsigned short* __restrict__ Qpk, unsigned short* __restrict__ Kpk,
    unsigned short* __restrict__ Vpk) {
  __shared__ __attribute__((aligned(16))) unsigned short shbuf[24576];  // 49152 B
  unsigned short* As = shbuf;            // 3 x [128*32] (24KB)
  unsigned short* Bs = shbuf + 12288;    // 3 x [128*32] (24KB)
  const int t = threadIdx.x, w = t >> 6, l = t & 63;
  const int wr = w >> 1, wc = w & 1;
  const int lrow = l & 15, lhi = l >> 4;
  const int row0 = blockIdx.y * 128, col0 = blockIdx.x * 128;
  const unsigned short* Ab = A + (size_t)row0 * K;
  const unsigned short* Bb = Bt + (size_t)col0 * K;
  const int srow = w * 32 + (l >> 2);
  const int scol = (l & 3) * 8;
  f32x4 z = {0.f, 0.f, 0.f, 0.f};
  f32x4 acc[4][4];
#pragma unroll
  for (int m = 0; m < 4; m++)
#pragma unroll
    for (int n = 0; n < 4; n++) acc[m][n] = z;

#define STAGE_G(tt, buf)                                                        \
  {                                                                             \
    const int k0_ = (tt) * 32;                                                  \
    async16(Ab + (size_t)srow * K + k0_ + scol,        &As[(buf) * 4096 + (w * 32) * 32]); \
    async16(Ab + (size_t)(srow + 16) * K + k0_ + scol, &As[(buf) * 4096 + (w * 32 + 16) * 32]); \
    async16(Bb + (size_t)srow * K + k0_ + scol,        &Bs[(buf) * 4096 + (w * 32) * 32]); \
    async16(Bb + (size_t)(srow + 16) * K + k0_ + scol, &Bs[(buf) * 4096 + (w * 32 + 16) * 32]); \
  }

  const int NT = K >> 5;                 // 64 for both GEMMs
  STAGE_G(0, 0);
  for (int tt = 0; tt < NT; tt++) {
    const int cur = tt % 3;
    if (tt + 1 < NT) {
      STAGE_G(tt + 1, (tt + 1) % 3);     // targets (tt+1)%3: disjoint from
      asm volatile("s_waitcnt vmcnt(4)" ::: "memory");  // (tt-1)%3 and tt%3
    } else {
      asm volatile("s_waitcnt vmcnt(0)" ::: "memory");
    }
    __builtin_amdgcn_s_barrier();        // the ONLY barrier per round
    __builtin_amdgcn_sched_barrier(0);
    bf16x8 af[4], bfr[4];
#pragma unroll
    for (int m = 0; m < 4; m++)
      af[m] = ldfrag(&As[cur * 4096 + (wr * 64 + m * 16 + lrow) * 32 + lhi * 8]);
#pragma unroll
    for (int n = 0; n < 4; n++)
      bfr[n] = ldfrag(&Bs[cur * 4096 + (wc * 64 + n * 16 + lrow) * 32 + lhi * 8]);
    __builtin_amdgcn_s_setprio(1);
#pragma unroll
    for (int m = 0; m < 4; m++)
#pragma unroll
      for (int n = 0; n < 4; n++)
        acc[m][n] = __builtin_amdgcn_mfma_f32_16x16x32_bf16(af[m], bfr[n], acc[m][n], 0, 0, 0);
    __builtin_amdgcn_s_setprio(0);
  }
#undef STAGE_G

  if (Qpk) {
    // ---------- fused mid epilogue ----------
    __syncthreads();   // all waves done with staging LDS before overlay reuse
    // acc -> LDS tile [128][132] bf16 (overlays dead staging)
#pragma unroll
    for (int m = 0; m < 4; m++)
#pragma unroll
      for (int n = 0; n < 4; n++)
#pragma unroll
        for (int r = 0; r < 4; r++)
          shbuf[(wr * 64 + m * 16 + lhi * 4 + r) * 132 + wc * 64 + n * 16 + lrow] =
              f2bf(acc[m][n][r]);
    __syncthreads();
    const int head = blockIdx.x;           // col-tile == head
    const int d0 = 2 * l;
    for (int rr = 0; rr < 32; rr++) {
      const int row = w * 32 + rr;
      const int bs = row0 + row;
      const int b = bs >> 11, s = bs & 2047;
      unsigned int uu = *(const unsigned int*)&shbuf[row * 132 + d0];
      float x0 = bf2f((unsigned short)(uu & 0xffffu));
      float x1 = bf2f((unsigned short)(uu >> 16));
      if (head < 20) {
        const float* nw = (head < 16) ? qw : kw;
        float ss = x0 * x0 + x1 * x1;
#pragma unroll
        for (int mk = 1; mk < 64; mk <<= 1) ss += __shfl_xor(ss, mk);
        float inv = rsqrtf(ss * (1.0f / 128.0f) + 1e-6f);
        float n0 = x0 * inv * nw[d0], n1 = x1 * inv * nw[d0 + 1];
        float p0 = __shfl_xor(n0, 32), p1 = __shfl_xor(n1, 32);
        float sg = (l < 32) ? -1.0f : 1.0f;
        float c0 = cosT[s * 128 + d0], c1 = cosT[s * 128 + d0 + 1];
        float sn0 = sinT[s * 128 + d0], sn1 = sinT[s * 128 + d0 + 1];
        float o0 = n0 * c0 + sg * p0 * sn0;
        float o1 = n1 * c1 + sg * p1 * sn1;
        int mf = d0 >> 4, hi = (d0 >> 3) & 1, j = d0 & 7;
        int blk = s >> 5, r31 = s & 31;
        int foff = (mf * 2 + hi) * 256 + r31 * 8 + j;
        unsigned short* dst;
        if (head < 16) {
          const float qs = 0.08838834764831845f * 1.4426950408889634f;  // 1/sqrt(128)*log2e
          o0 *= qs; o1 *= qs;
          dst = Qpk + (((size_t)(b * 16 + head)) * 64 + blk) * 4096 + foff;
        } else {
          dst = Kpk + (((size_t)(b * 4 + (head - 16))) * 64 + blk) * 4096 + foff;
        }
        *(unsigned int*)dst = pk2(o0, o1);
      } else {
        int kvh = head - 20;
        int blk = s >> 5, ks = (s >> 4) & 1, his = (s >> 3) & 1, j = s & 7;
        int n = d0 >> 5, d31 = d0 & 31;
        size_t base = (((size_t)(b * 4 + kvh)) * 64 + blk) * 4096 +
                      (((n * 2 + ks) * 2 + his) * 256 + d31 * 8 + j);
        Vpk[base] = f2bf(x0);
        Vpk[base + 8] = f2bf(x1);   // d0+1 -> d31+1
      }
    }
  } else if (out_bf16) {
    unsigned short* C = (unsigned short*)Cout;
#pragma unroll
    for (int m = 0; m < 4; m++)
#pragma unroll
      for (int n = 0; n < 4; n++)
#pragma unroll
        for (int r = 0; r < 4; r++) {
          size_t grow = row0 + wr * 64 + m * 16 + lhi * 4 + r;
          size_t gcol = col0 + wc * 64 + n * 16 + lrow;
          C[grow * N + gcol] = f2bf(acc[m][n][r]);
        }
  } else {
    float* C = (float*)Cout;
#pragma unroll
    for (int m = 0; m < 4; m++)
#pragma unroll
      for (int n = 0; n < 4; n++)
#pragma unroll
        for (int r = 0; r < 4; r++) {
          size_t grow = row0 + wr * 64 + m * 16 + lhi * 4 + r;
          size_t gcol = col0 + wc * 64 + n * 16 + lrow;
          C[grow * N + gcol] = acc[m][n][r];
        }
  }
}

// ---------------- flash attention: 8-wave KV-split, triple-buf, 1 barrier/round ----
// (r14 structure, verbatim.) 256 blocks x 8 waves (512 thr). bid&7 -> (b,kvh)
// (XCD-pinned K/V); pj=bid>>3: block runs strip 63-pj then strip pj (33-34
// rounds each, equal). Waves: grp = w>>2 (KV-half), hw = w&3 (head). Private
// online softmax per group; 2-way in-LDS flash combine at strip end (cold
// path, __syncthreads). Staging: 3 bufs x 2 grps x 16KB, one s_barrier per
// round. Softmax fmax/sum as trees.
// LDS: [0,98304) staging; epilogue obuf overlays dead staging; mlb at
// [98304,100352).
__global__ __launch_bounds__(512) void attn_kernel(
    const unsigned short* __restrict__ Qpk, const unsigned short* __restrict__ Kpk,
    const unsigned short* __restrict__ Vpk, unsigned short* __restrict__ Y) {
  __shared__ __attribute__((aligned(16))) unsigned char lds_raw[100352];
  const int t = threadIdx.x, w = t >> 6, l = t & 63;
  const int q31 = l & 31, hi = l >> 5;
  const int grp = w >> 2, hw = w & 3;
  const int bid = blockIdx.x;
  const int xcd = bid & 7;
  const int b = xcd >> 2, kvh = xcd & 3;
  const int hd = kvh * 4 + hw;
  const int bh = b * 16 + hd;
  const int pj = bid >> 3;
  const unsigned short* Kg = Kpk + (size_t)(b * 4 + kvh) * 262144;
  const unsigned short* Vg = Vpk + (size_t)(b * 4 + kvh) * 262144;
  float* mlb = (float*)(lds_raw + 98304);   // [head][grp][{m,l}][q31], 2KB

#define STAGE1(st, buf)                                                        \
  {                                                                            \
    unsigned char* base_ = lds_raw + ((buf) * 2 + grp) * 16384;                \
    const unsigned short* kg_ = Kg + (size_t)(st) * 4096;                      \
    const unsigned short* vg_ = Vg + (size_t)(st) * 4096;                      \
    _Pragma("unroll")                                                          \
    for (int i_ = 0; i_ < 4; i_++) {                                           \
      int c_ = hw * 4 + i_;                                                    \
      const unsigned short* src_ = (c_ < 8) ? (kg_ + c_ * 512 + l * 8)         \
                                            : (vg_ + (c_ - 8) * 512 + l * 8);  \
      async16(src_, base_ + c_ * 1024 + l * 16);                               \
    }                                                                          \
  }

  for (int phase = 0; phase < 2; phase++) {
    const int strip = phase ? pj : (63 - pj);
    const int q0w = strip * 32;
    const int qg = q0w + q31;
    const int nt = strip + 1;
    const int hcut = (nt + 1) >> 1;
    const int myFirst = grp ? hcut : 0;
    const int myCnt = grp ? (nt - hcut) : hcut;
    const int R = hcut;

    const unsigned short* Qs = Qpk + (((size_t)bh * 64 + strip) * 4096) + (size_t)l * 8;
    bf16x8 qf[8];
#pragma unroll
    for (int mf = 0; mf < 8; mf++) qf[mf] = ldfrag(Qs + mf * 512);
    asm volatile("s_waitcnt vmcnt(0)" ::: "memory");  // Q resolved; vmcnt exact

    { int st0 = (myCnt > 0) ? myFirst : 0; STAGE1(st0, 0); }

    f32x16 o[4];
#pragma unroll
    for (int n = 0; n < 4; n++) o[n] = zero16();
    float m = -3.0e38f, lsum = 0.f;

    for (int r = 0; r < R; r++) {
      const int buf = r % 3;
      { int st = (r + 1 < myCnt) ? (myFirst + r + 1) : 0; STAGE1(st, (r + 1) % 3); }
      asm volatile("s_waitcnt vmcnt(4)" ::: "memory");  // my round-r stage landed
      __builtin_amdgcn_s_barrier();
      __builtin_amdgcn_sched_barrier(0);

      if (r < myCnt) {
        const int ti = myFirst + r;
        const int kv0 = ti << 5;
        const unsigned short* base =
            (const unsigned short*)(lds_raw + (buf * 2 + grp) * 16384);
        // ---- QK^T (swapped): two 4-deep chains, then merge ----
        f32x16 sA = zero16(), sB = zero16();
        __builtin_amdgcn_s_setprio(1);
#pragma unroll
        for (int mf = 0; mf < 4; mf++) {
          sA = mfma32(ldfrag(base + mf * 512 + l * 8), qf[mf], sA);
          sB = mfma32(ldfrag(base + (mf + 4) * 512 + l * 8), qf[mf + 4], sB);
        }
        __builtin_amdgcn_s_setprio(0);
#pragma unroll
        for (int rr = 0; rr < 16; rr++) sA[rr] += sB[rr];
        // ---- causal mask (diagonal tile only; tile nt-1 has kv0 == q0w) ----
        if (ti == nt - 1) {
#pragma unroll
          for (int rr = 0; rr < 16; rr++) {
            int kv = kv0 + (rr & 3) + 8 * (rr >> 2) + 4 * hi;
            if (kv > qg) sA[rr] = -3.0e38f;
          }
        }
        // ---- online softmax (lane-local row, exp2 units), TREE reductions ----
        float a0 = fmaxf(sA[0], sA[1]),   a1 = fmaxf(sA[2], sA[3]);
        float a2 = fmaxf(sA[4], sA[5]),   a3 = fmaxf(sA[6], sA[7]);
        float a4 = fmaxf(sA[8], sA[9]),   a5 = fmaxf(sA[10], sA[11]);
        float a6 = fmaxf(sA[12], sA[13]), a7 = fmaxf(sA[14], sA[15]);
        a0 = fmaxf(fmaxf(a0, a1), a2);    // v_max3-fusable
        a3 = fmaxf(fmaxf(a3, a4), a5);
        a6 = fmaxf(a6, a7);
        float pm = fmaxf(fmaxf(a0, a3), a6);
        pm = fmaxf(pm, __shfl_xor(pm, 32));
        if (__any(pm > m + 8.0f)) {   // defer-max
          float mn = fmaxf(m, pm);
          float scl = exp2f(m - mn);
          m = mn; lsum *= scl;
#pragma unroll
          for (int rr = 0; rr < 16; rr++) {
            float sr = __shfl(scl, (rr & 3) + 8 * (rr >> 2) + 4 * hi);
            o[0][rr] *= sr; o[1][rr] *= sr; o[2][rr] *= sr; o[3][rr] *= sr;
          }
        }
#pragma unroll
        for (int rr = 0; rr < 16; rr++) sA[rr] = exp2f(sA[rr] - m);
        float s0 = (sA[0] + sA[1]) + (sA[2] + sA[3]);
        float s1 = (sA[4] + sA[5]) + (sA[6] + sA[7]);
        float s2 = (sA[8] + sA[9]) + (sA[10] + sA[11]);
        float s3 = (sA[12] + sA[13]) + (sA[14] + sA[15]);
        float ts = (s0 + s1) + (s2 + s3);
        ts += __shfl_xor(ts, 32);
        lsum += ts;
        // ---- pack P -> A-operand fragments (register exchange) ----
        bf16x8 paf[2];
#pragma unroll
        for (int f = 0; f < 2; f++) {
          const int bs8 = 8 * f;
          unsigned g00 = cvtpk(sA[bs8 + 0], sA[bs8 + 1]);
          unsigned g01 = cvtpk(sA[bs8 + 2], sA[bs8 + 3]);
          unsigned g10 = cvtpk(sA[bs8 + 4], sA[bs8 + 5]);
          unsigned g11 = cvtpk(sA[bs8 + 6], sA[bs8 + 7]);
          unsigned snd0 = hi ? g00 : g10;
          unsigned snd1 = hi ? g01 : g11;
          unsigned r0 = (unsigned)__shfl_xor((int)snd0, 32);
          unsigned r1 = (unsigned)__shfl_xor((int)snd1, 32);
          unsigned own0 = hi ? g10 : g00;
          unsigned own1 = hi ? g11 : g01;
          u32x4 wv;
          wv.x = hi ? r0 : own0;
          wv.y = hi ? r1 : own1;
          wv.z = hi ? own0 : r0;
          wv.w = hi ? own1 : r1;
          paf[f] = __builtin_bit_cast(bf16x8, wv);
        }
        // ---- PV ----
        __builtin_amdgcn_s_setprio(1);
#pragma unroll
        for (int n = 0; n < 4; n++) {
          o[n] = mfma32(paf[0], ldfrag(base + 4096 + (n * 2 + 0) * 512 + l * 8), o[n]);
          o[n] = mfma32(paf[1], ldfrag(base + 4096 + (n * 2 + 1) * 512 + l * 8), o[n]);
        }
        __builtin_amdgcn_s_setprio(0);
      }
      // no second barrier: triple buffer makes the restage safe
    }

    // ---- combine the two KV-half partials (in LDS; cold path, full syncs) ----
    __syncthreads();
    if (l < 32) {
      mlb[hw * 128 + grp * 64 + q31] = m;
      mlb[hw * 128 + grp * 64 + 32 + q31] = lsum;
    }
    __syncthreads();
    float m_o = mlb[hw * 128 + (grp ^ 1) * 64 + q31];
    float l_o = mlb[hw * 128 + (grp ^ 1) * 64 + 32 + q31];
    float M = fmaxf(m, m_o);
    float sc = exp2f(m - M);
    float lF = lsum * sc + l_o * exp2f(m_o - M);
#pragma unroll
    for (int rr = 0; rr < 16; rr++) {
      float sr = __shfl(sc, (rr & 3) + 8 * (rr >> 2) + 4 * hi);
      o[0][rr] *= sr; o[1][rr] *= sr; o[2][rr] *= sr; o[3][rr] *= sr;
    }
    float* ob = (float*)lds_raw + hw * 4096;   // [q32][d128] per head (staging dead now)
    if (grp == 1) {
#pragma unroll
      for (int rr = 0; rr < 16; rr++) {
        int cr = (rr & 3) + 8 * (rr >> 2) + 4 * hi;
#pragma unroll
        for (int n = 0; n < 4; n++) ob[cr * 128 + n * 32 + q31] = o[n][rr];
      }
    }
    __syncthreads();
    if (grp == 0) {
      float linv = 1.0f / lF;
#pragma unroll
      for (int rr = 0; rr < 16; rr++) {
        int cr = (rr & 3) + 8 * (rr >> 2) + 4 * hi;
        float lr = __shfl(linv, cr);
        int qrow = q0w + cr;
        size_t rowoff = ((size_t)(b * S_LEN + qrow)) * 2048 + hd * 128 + q31;
        Y[rowoff]      = f2bf((o[0][rr] + ob[cr * 128 + q31]) * lr);
        Y[rowoff + 32] = f2bf((o[1][rr] + ob[cr * 128 + 32 + q31]) * lr);
        Y[rowoff + 64] = f2bf((o[2][rr] + ob[cr * 128 + 64 + q31]) * lr);
        Y[rowoff + 96] = f2bf((o[3][rr] + ob[cr * 128 + 96 + q31]) * lr);
      }
    }
    __syncthreads();   // obuf consumed before next phase restages
  }
#undef STAGE1
}

// ---------------- launch ----------------
extern "C" void kernel_launch(void* const* d_in, const int* in_sizes, int n_in,
                              void* d_out, int out_size, void* d_ws, size_t ws_size,
                              hipStream_t stream) {
  const float* x  = (const float*)d_in[0];
  const float* rc = (const float*)d_in[1];
  const float* rs = (const float*)d_in[2];
  const float* Wq = (const float*)d_in[3];
  const float* Wk = (const float*)d_in[4];
  const float* Wv = (const float*)d_in[5];
  const float* Wo = (const float*)d_in[6];
  const float* qw = (const float*)d_in[7];
  const float* kw = (const float*)d_in[8];
  float* out = (float*)d_out;
  char* ws = (char*)d_ws;

  unsigned short* xb   = (unsigned short*)(ws + 0);          // live: prep + QKV GEMM
  unsigned short* WT   = (unsigned short*)(ws + 16777216);   // live: QKV GEMM
  unsigned short* WoT  = (unsigned short*)(ws + 29360128);   // live: until out GEMM
  unsigned short* Qpk  = (unsigned short*)(ws + 37748736);   // 16MB
  unsigned short* Kpk  = (unsigned short*)(ws + 54525952);   // 4MB
  unsigned short* Vpk  = (unsigned short*)(ws + 58720256);   // 4MB
  unsigned short* Yb   = (unsigned short*)(ws + 0);          // over xb (dead after QKV GEMM)

  prep_kernel<<<6656, 256, 0, stream>>>(x, Wq, Wk, Wv, Wo, xb, WT, WoT);
  gemm_bf16_kernel<<<dim3(24, 32), 256, 0, stream>>>(
      xb, WT, nullptr, 4096, 3072, 2048, 1, rc, rs, qw, kw, Qpk, Kpk, Vpk);
  attn_kernel<<<256, 512, 0, stream>>>(Qpk, Kpk, Vpk, Yb);
  gemm_bf16_kernel<<<dim3(16, 32), 256, 0, stream>>>(
      Yb, WoT, out, 4096, 2048, 2048, 0, nullptr, nullptr, nullptr, nullptr,
      nullptr, nullptr, nullptr);
}

// Round 21
// 208.445 us; speedup vs baseline: 1.2832x; 1.0192x over previous
//
#include <hip/hip_runtime.h>

// CausalSelfAttention: B=2,S=2048,H=2048,NH=16,NKV=4,HD=128, fp32 in/out,
// internal bf16 MFMA pipeline.
// Round 21 = Round 20 + T1 XCD-aware swizzle on both GEMM grids.
// r18-r20: conflicts/depth/barriers all null -> GEMM is latency-bound with
// FETCH 88.8MB vs 29.4 ideal (3x over-fetch: consecutive blocks share an
// A-panel but scatter across 8 XCD L2s). Swizzle n'=(bid&7)*(n/8)+(bid>>3)
// gives each XCD 4 EXCLUSIVE A row-panels x all cols: A-panels fetched once,
// L2-resident, reused 24x (QKV) / 16x (out). Bijective: 768%8==0, 512%8==0.
// attn = r14 structure verbatim (81us).
// ws layout (bytes), total 62,914,560:
//   [0,16.8M)          xb (live: prep+QKV GEMM) -> later Yb
//   [16.8M,29.36M)     WqkvT bf16 [3072][2048] (live: QKV GEMM)
//   [29.36M,37.75M)    WoT bf16 [2048][2048]   (live: until out GEMM)
//   [37.75M,54.53M)    Qpk (16MB)   [54.53M,58.72M) Kpk   [58.72M,62.91M) Vpk

#define S_LEN 2048

typedef __bf16 bf16_t;
typedef bf16_t bf16x8 __attribute__((ext_vector_type(8)));
typedef float f32x4 __attribute__((ext_vector_type(4)));
typedef float f32x16 __attribute__((ext_vector_type(16)));
typedef unsigned int u32x4 __attribute__((ext_vector_type(4)));
typedef unsigned short u16x4 __attribute__((ext_vector_type(4)));

__device__ __forceinline__ unsigned short f2bf(float f) {
  unsigned int u = __builtin_bit_cast(unsigned int, f);
  u += 0x7fffu + ((u >> 16) & 1u);
  return (unsigned short)(u >> 16);
}
__device__ __forceinline__ float bf2f(unsigned short h) {
  return __builtin_bit_cast(float, (unsigned int)h << 16);
}
__device__ __forceinline__ unsigned pk2(float a, float b) {
  return (unsigned)f2bf(a) | ((unsigned)f2bf(b) << 16);
}
// HW packed convert: lo = bf16(a), hi = bf16(b). Single VALU instruction.
__device__ __forceinline__ unsigned cvtpk(float a, float b) {
  unsigned r;
  asm("v_cvt_pk_bf16_f32 %0, %1, %2" : "=v"(r) : "v"(a), "v"(b));
  return r;
}

typedef const __attribute__((address_space(1))) unsigned int* gas1_t;
typedef __attribute__((address_space(3))) unsigned int* las3_t;
__device__ __forceinline__ void async16(const void* g, void* l) {
  __builtin_amdgcn_global_load_lds((gas1_t)g, (las3_t)l, 16, 0, 0);
}

__device__ __forceinline__ bf16x8 ldfrag(const void* p) {
  return __builtin_bit_cast(bf16x8, *(const u32x4*)p);
}
__device__ __forceinline__ f32x16 mfma32(bf16x8 a, bf16x8 b, f32x16 c) {
  return __builtin_amdgcn_mfma_f32_32x32x16_bf16(a, b, c, 0, 0, 0);
}
__device__ __forceinline__ f32x16 zero16() {
  f32x16 v;
#pragma unroll
  for (int i = 0; i < 16; i++) v[i] = 0.f;
  return v;
}

// ---------------- fused prep: cast x + 4 weight transposes ----------------
__device__ __forceinline__ void transpose_body(
    const float* __restrict__ in, unsigned short* __restrict__ out,
    int C, int out_row_off, int out_ld, int bx, int by, int t,
    unsigned short (*L)[68]) {
  int r0 = by * 64, c0 = bx * 64;
#pragma unroll
  for (int i = 0; i < 4; i++) {
    int r = i * 16 + (t >> 4);
    int c = (t & 15) * 4;
    f32x4 v = *(const f32x4*)&in[(size_t)(r0 + r) * C + c0 + c];
    u16x4 u;
    u.x = f2bf(v.x); u.y = f2bf(v.y); u.z = f2bf(v.z); u.w = f2bf(v.w);
    *(u16x4*)&L[r][c] = u;
  }
  __syncthreads();
#pragma unroll
  for (int i = 0; i < 4; i++) {
    int oc = i * 16 + (t >> 4);
    int orr = (t & 15) * 4;
    u16x4 u;
    u.x = L[orr + 0][oc]; u.y = L[orr + 1][oc];
    u.z = L[orr + 2][oc]; u.w = L[orr + 3][oc];
    *(u16x4*)&out[(size_t)(c0 + oc + out_row_off) * out_ld + r0 + orr] = u;
  }
}

__global__ __launch_bounds__(256) void prep_kernel(
    const float* __restrict__ x, const float* __restrict__ Wq,
    const float* __restrict__ Wk, const float* __restrict__ Wv,
    const float* __restrict__ Wo, unsigned short* __restrict__ xb,
    unsigned short* __restrict__ WT, unsigned short* __restrict__ WoT) {
  __shared__ unsigned short L[64][68];
  const int bid = blockIdx.x, t = threadIdx.x;
  if (bid < 4096) {                       // cast x: 1048576 x 8 elems
    int i = bid * 256 + t;
    const f32x4* p = (const f32x4*)x + (size_t)i * 2;
    f32x4 a = p[0], b = p[1];
    u32x4 o;
    o.x = pk2(a.x, a.y);
    o.y = pk2(a.z, a.w);
    o.z = pk2(b.x, b.y);
    o.w = pk2(b.z, b.w);
    *(u32x4*)(xb + (size_t)i * 8) = o;
  } else if (bid < 5120) {                // Wq^T -> WT rows [0,2048)
    int id = bid - 4096;
    transpose_body(Wq, WT, 2048, 0, 2048, id & 31, id >> 5, t, L);
  } else if (bid < 5376) {                // Wk^T -> WT rows [2048,2560)
    int id = bid - 5120;
    transpose_body(Wk, WT, 512, 2048, 2048, id & 7, id >> 3, t, L);
  } else if (bid < 5632) {                // Wv^T -> WT rows [2560,3072)
    int id = bid - 5376;
    transpose_body(Wv, WT, 512, 2560, 2048, id & 7, id >> 3, t, L);
  } else {                                // Wo^T -> WoT
    int id = bid - 5632;
    transpose_body(Wo, WoT, 2048, 0, 2048, id & 31, id >> 5, t, L);
  }
}

// ---------------- bf16 GEMM (+ optional fused mid epilogue) ----------------
// C[M][N] = A[M][K]*Bt[N][K]^T. 128x128 tile, BK=32, row-major staging,
// triple-buffered, one barrier per K-round (r20). 1D grid with T1 XCD
// swizzle: n'=(bid&7)*(nb/8)+(bid>>3); bx=n'%NBX, by=n'/NBX -> each XCD
// owns 4 exclusive A row-panels (L2-resident, reused across all cols).
// If Qpk!=nullptr (QKV GEMM): col-tile bx == head; fused RMSNorm+RoPE+
// packing epilogue via [128][132] LDS overlay.
__global__ __launch_bounds__(256) void gemm_bf16_kernel(
    const unsigned short* __restrict__ A, const unsigned short* __restrict__ Bt,
    void* __restrict__ Cout, int M, int N, int K, int NBX, int out_bf16,
    const float* __restrict__ cosT, const float* __restrict__ sinT,
    const float* __restrict__ qw, const float* __restrict__ kw,
    unsigned short* __restrict__ Qpk, unsigned short* __restrict__ Kpk,
    unsigned short* __restrict__ Vpk) {
  __shared__ __attribute__((aligned(16))) unsigned short shbuf[24576];  // 49152 B
  unsigned short* As = shbuf;            // 3 x [128*32] (24KB)
  unsigned short* Bs = shbuf + 12288;    // 3 x [128*32] (24KB)
  const int t = threadIdx.x, w = t >> 6, l = t & 63;
  const int wr = w >> 1, wc = w & 1;
  const int lrow = l & 15, lhi = l >> 4;
  // T1 XCD swizzle (bijective: gridDim.x % 8 == 0)
  const int nb = gridDim.x;
  const int nsw = (blockIdx.x & 7) * (nb >> 3) + (blockIdx.x >> 3);
  const int bx = nsw % NBX, by = nsw / NBX;
  const int row0 = by * 128, col0 = bx * 128;
  const unsigned short* Ab = A + (size_t)row0 * K;
  const unsigned short* Bb = Bt + (size_t)col0 * K;
  const int srow = w * 32 + (l >> 2);
  const int scol = (l & 3) * 8;
  f32x4 z = {0.f, 0.f, 0.f, 0.f};
  f32x4 acc[4][4];
#pragma unroll
  for (int m = 0; m < 4; m++)
#pragma unroll
    for (int n = 0; n < 4; n++) acc[m][n] = z;

#define STAGE_G(tt, buf)                                                        \
  {                                                                             \
    const int k0_ = (tt) * 32;                                                  \
    async16(Ab + (size_t)srow * K + k0_ + scol,        &As[(buf) * 4096 + (w * 32) * 32]); \
    async16(Ab + (size_t)(srow + 16) * K + k0_ + scol, &As[(buf) * 4096 + (w * 32 + 16) * 32]); \
    async16(Bb + (size_t)srow * K + k0_ + scol,        &Bs[(buf) * 4096 + (w * 32) * 32]); \
    async16(Bb + (size_t)(srow + 16) * K + k0_ + scol, &Bs[(buf) * 4096 + (w * 32 + 16) * 32]); \
  }

  const int NT = K >> 5;                 // 64 for both GEMMs
  STAGE_G(0, 0);
  for (int tt = 0; tt < NT; tt++) {
    const int cur = tt % 3;
    if (tt + 1 < NT) {
      STAGE_G(tt + 1, (tt + 1) % 3);     // targets (tt+1)%3: disjoint from
      asm volatile("s_waitcnt vmcnt(4)" ::: "memory");  // (tt-1)%3 and tt%3
    } else {
      asm volatile("s_waitcnt vmcnt(0)" ::: "memory");
    }
    __builtin_amdgcn_s_barrier();        // the ONLY barrier per round
    __builtin_amdgcn_sched_barrier(0);
    bf16x8 af[4], bfr[4];
#pragma unroll
    for (int m = 0; m < 4; m++)
      af[m] = ldfrag(&As[cur * 4096 + (wr * 64 + m * 16 + lrow) * 32 + lhi * 8]);
#pragma unroll
    for (int n = 0; n < 4; n++)
      bfr[n] = ldfrag(&Bs[cur * 4096 + (wc * 64 + n * 16 + lrow) * 32 + lhi * 8]);
    __builtin_amdgcn_s_setprio(1);
#pragma unroll
    for (int m = 0; m < 4; m++)
#pragma unroll
      for (int n = 0; n < 4; n++)
        acc[m][n] = __builtin_amdgcn_mfma_f32_16x16x32_bf16(af[m], bfr[n], acc[m][n], 0, 0, 0);
    __builtin_amdgcn_s_setprio(0);
  }
#undef STAGE_G

  if (Qpk) {
    // ---------- fused mid epilogue ----------
    __syncthreads();   // all waves done with staging LDS before overlay reuse
    // acc -> LDS tile [128][132] bf16 (overlays dead staging)
#pragma unroll
    for (int m = 0; m < 4; m++)
#pragma unroll
      for (int n = 0; n < 4; n++)
#pragma unroll
        for (int r = 0; r < 4; r++)
          shbuf[(wr * 64 + m * 16 + lhi * 4 + r) * 132 + wc * 64 + n * 16 + lrow] =
              f2bf(acc[m][n][r]);
    __syncthreads();
    const int head = bx;                   // col-tile == head
    const int d0 = 2 * l;
    for (int rr = 0; rr < 32; rr++) {
      const int row = w * 32 + rr;
      const int bs = row0 + row;
      const int b = bs >> 11, s = bs & 2047;
      unsigned int uu = *(const unsigned int*)&shbuf[row * 132 + d0];
      float x0 = bf2f((unsigned short)(uu & 0xffffu));
      float x1 = bf2f((unsigned short)(uu >> 16));
      if (head < 20) {
        const float* nw = (head < 16) ? qw : kw;
        float ss = x0 * x0 + x1 * x1;
#pragma unroll
        for (int mk = 1; mk < 64; mk <<= 1) ss += __shfl_xor(ss, mk);
        float inv = rsqrtf(ss * (1.0f / 128.0f) + 1e-6f);
        float n0 = x0 * inv * nw[d0], n1 = x1 * inv * nw[d0 + 1];
        float p0 = __shfl_xor(n0, 32), p1 = __shfl_xor(n1, 32);
        float sg = (l < 32) ? -1.0f : 1.0f;
        float c0 = cosT[s * 128 + d0], c1 = cosT[s * 128 + d0 + 1];
        float sn0 = sinT[s * 128 + d0], sn1 = sinT[s * 128 + d0 + 1];
        float o0 = n0 * c0 + sg * p0 * sn0;
        float o1 = n1 * c1 + sg * p1 * sn1;
        int mf = d0 >> 4, hi = (d0 >> 3) & 1, j = d0 & 7;
        int blk = s >> 5, r31 = s & 31;
        int foff = (mf * 2 + hi) * 256 + r31 * 8 + j;
        unsigned short* dst;
        if (head < 16) {
          const float qs = 0.08838834764831845f * 1.4426950408889634f;  // 1/sqrt(128)*log2e
          o0 *= qs; o1 *= qs;
          dst = Qpk + (((size_t)(b * 16 + head)) * 64 + blk) * 4096 + foff;
        } else {
          dst = Kpk + (((size_t)(b * 4 + (head - 16))) * 64 + blk) * 4096 + foff;
        }
        *(unsigned int*)dst = pk2(o0, o1);
      } else {
        int kvh = head - 20;
        int blk = s >> 5, ks = (s >> 4) & 1, his = (s >> 3) & 1, j = s & 7;
        int n = d0 >> 5, d31 = d0 & 31;
        size_t base = (((size_t)(b * 4 + kvh)) * 64 + blk) * 4096 +
                      (((n * 2 + ks) * 2 + his) * 256 + d31 * 8 + j);
        Vpk[base] = f2bf(x0);
        Vpk[base + 8] = f2bf(x1);   // d0+1 -> d31+1
      }
    }
  } else if (out_bf16) {
    unsigned short* C = (unsigned short*)Cout;
#pragma unroll
    for (int m = 0; m < 4; m++)
#pragma unroll
      for (int n = 0; n < 4; n++)
#pragma unroll
        for (int r = 0; r < 4; r++) {
          size_t grow = row0 + wr * 64 + m * 16 + lhi * 4 + r;
          size_t gcol = col0 + wc * 64 + n * 16 + lrow;
          C[grow * N + gcol] = f2bf(acc[m][n][r]);
        }
  } else {
    float* C = (float*)Cout;
#pragma unroll
    for (int m = 0; m < 4; m++)
#pragma unroll
      for (int n = 0; n < 4; n++)
#pragma unroll
        for (int r = 0; r < 4; r++) {
          size_t grow = row0 + wr * 64 + m * 16 + lhi * 4 + r;
          size_t gcol = col0 + wc * 64 + n * 16 + lrow;
          C[grow * N + gcol] = acc[m][n][r];
        }
  }
}

// ---------------- flash attention: 8-wave KV-split, triple-buf, 1 barrier/round ----
// (r14 structure, verbatim.) 256 blocks x 8 waves (512 thr). bid&7 -> (b,kvh)
// (XCD-pinned K/V); pj=bid>>3: block runs strip 63-pj then strip pj (33-34
// rounds each, equal). Waves: grp = w>>2 (KV-half), hw = w&3 (head). Private
// online softmax per group; 2-way in-LDS flash combine at strip end (cold
// path, __syncthreads). Staging: 3 bufs x 2 grps x 16KB, one s_barrier per
// round. Softmax fmax/sum as trees.
// LDS: [0,98304) staging; epilogue obuf overlays dead staging; mlb at
// [98304,100352).
__global__ __launch_bounds__(512) void attn_kernel(
    const unsigned short* __restrict__ Qpk, const unsigned short* __restrict__ Kpk,
    const unsigned short* __restrict__ Vpk, unsigned short* __restrict__ Y) {
  __shared__ __attribute__((aligned(16))) unsigned char lds_raw[100352];
  const int t = threadIdx.x, w = t >> 6, l = t & 63;
  const int q31 = l & 31, hi = l >> 5;
  const int grp = w >> 2, hw = w & 3;
  const int bid = blockIdx.x;
  const int xcd = bid & 7;
  const int b = xcd >> 2, kvh = xcd & 3;
  const int hd = kvh * 4 + hw;
  const int bh = b * 16 + hd;
  const int pj = bid >> 3;
  const unsigned short* Kg = Kpk + (size_t)(b * 4 + kvh) * 262144;
  const unsigned short* Vg = Vpk + (size_t)(b * 4 + kvh) * 262144;
  float* mlb = (float*)(lds_raw + 98304);   // [head][grp][{m,l}][q31], 2KB

#define STAGE1(st, buf)                                                        \
  {                                                                            \
    unsigned char* base_ = lds_raw + ((buf) * 2 + grp) * 16384;                \
    const unsigned short* kg_ = Kg + (size_t)(st) * 4096;                      \
    const unsigned short* vg_ = Vg + (size_t)(st) * 4096;                      \
    _Pragma("unroll")                                                          \
    for (int i_ = 0; i_ < 4; i_++) {                                           \
      int c_ = hw * 4 + i_;                                                    \
      const unsigned short* src_ = (c_ < 8) ? (kg_ + c_ * 512 + l * 8)         \
                                            : (vg_ + (c_ - 8) * 512 + l * 8);  \
      async16(src_, base_ + c_ * 1024 + l * 16);                               \
    }                                                                          \
  }

  for (int phase = 0; phase < 2; phase++) {
    const int strip = phase ? pj : (63 - pj);
    const int q0w = strip * 32;
    const int qg = q0w + q31;
    const int nt = strip + 1;
    const int hcut = (nt + 1) >> 1;
    const int myFirst = grp ? hcut : 0;
    const int myCnt = grp ? (nt - hcut) : hcut;
    const int R = hcut;

    const unsigned short* Qs = Qpk + (((size_t)bh * 64 + strip) * 4096) + (size_t)l * 8;
    bf16x8 qf[8];
#pragma unroll
    for (int mf = 0; mf < 8; mf++) qf[mf] = ldfrag(Qs + mf * 512);
    asm volatile("s_waitcnt vmcnt(0)" ::: "memory");  // Q resolved; vmcnt exact

    { int st0 = (myCnt > 0) ? myFirst : 0; STAGE1(st0, 0); }

    f32x16 o[4];
#pragma unroll
    for (int n = 0; n < 4; n++) o[n] = zero16();
    float m = -3.0e38f, lsum = 0.f;

    for (int r = 0; r < R; r++) {
      const int buf = r % 3;
      { int st = (r + 1 < myCnt) ? (myFirst + r + 1) : 0; STAGE1(st, (r + 1) % 3); }
      asm volatile("s_waitcnt vmcnt(4)" ::: "memory");  // my round-r stage landed
      __builtin_amdgcn_s_barrier();
      __builtin_amdgcn_sched_barrier(0);

      if (r < myCnt) {
        const int ti = myFirst + r;
        const int kv0 = ti << 5;
        const unsigned short* base =
            (const unsigned short*)(lds_raw + (buf * 2 + grp) * 16384);
        // ---- QK^T (swapped): two 4-deep chains, then merge ----
        f32x16 sA = zero16(), sB = zero16();
        __builtin_amdgcn_s_setprio(1);
#pragma unroll
        for (int mf = 0; mf < 4; mf++) {
          sA = mfma32(ldfrag(base + mf * 512 + l * 8), qf[mf], sA);
          sB = mfma32(ldfrag(base + (mf + 4) * 512 + l * 8), qf[mf + 4], sB);
        }
        __builtin_amdgcn_s_setprio(0);
#pragma unroll
        for (int rr = 0; rr < 16; rr++) sA[rr] += sB[rr];
        // ---- causal mask (diagonal tile only; tile nt-1 has kv0 == q0w) ----
        if (ti == nt - 1) {
#pragma unroll
          for (int rr = 0; rr < 16; rr++) {
            int kv = kv0 + (rr & 3) + 8 * (rr >> 2) + 4 * hi;
            if (kv > qg) sA[rr] = -3.0e38f;
          }
        }
        // ---- online softmax (lane-local row, exp2 units), TREE reductions ----
        float a0 = fmaxf(sA[0], sA[1]),   a1 = fmaxf(sA[2], sA[3]);
        float a2 = fmaxf(sA[4], sA[5]),   a3 = fmaxf(sA[6], sA[7]);
        float a4 = fmaxf(sA[8], sA[9]),   a5 = fmaxf(sA[10], sA[11]);
        float a6 = fmaxf(sA[12], sA[13]), a7 = fmaxf(sA[14], sA[15]);
        a0 = fmaxf(fmaxf(a0, a1), a2);    // v_max3-fusable
        a3 = fmaxf(fmaxf(a3, a4), a5);
        a6 = fmaxf(a6, a7);
        float pm = fmaxf(fmaxf(a0, a3), a6);
        pm = fmaxf(pm, __shfl_xor(pm, 32));
        if (__any(pm > m + 8.0f)) {   // defer-max
          float mn = fmaxf(m, pm);
          float scl = exp2f(m - mn);
          m = mn; lsum *= scl;
#pragma unroll
          for (int rr = 0; rr < 16; rr++) {
            float sr = __shfl(scl, (rr & 3) + 8 * (rr >> 2) + 4 * hi);
            o[0][rr] *= sr; o[1][rr] *= sr; o[2][rr] *= sr; o[3][rr] *= sr;
          }
        }
#pragma unroll
        for (int rr = 0; rr < 16; rr++) sA[rr] = exp2f(sA[rr] - m);
        float s0 = (sA[0] + sA[1]) + (sA[2] + sA[3]);
        float s1 = (sA[4] + sA[5]) + (sA[6] + sA[7]);
        float s2 = (sA[8] + sA[9]) + (sA[10] + sA[11]);
        float s3 = (sA[12] + sA[13]) + (sA[14] + sA[15]);
        float ts = (s0 + s1) + (s2 + s3);
        ts += __shfl_xor(ts, 32);
        lsum += ts;
        // ---- pack P -> A-operand fragments (register exchange) ----
        bf16x8 paf[2];
#pragma unroll
        for (int f = 0; f < 2; f++) {
          const int bs8 = 8 * f;
          unsigned g00 = cvtpk(sA[bs8 + 0], sA[bs8 + 1]);
          unsigned g01 = cvtpk(sA[bs8 + 2], sA[bs8 + 3]);
          unsigned g10 = cvtpk(sA[bs8 + 4], sA[bs8 + 5]);
          unsigned g11 = cvtpk(sA[bs8 + 6], sA[bs8 + 7]);
          unsigned snd0 = hi ? g00 : g10;
          unsigned snd1 = hi ? g01 : g11;
          unsigned r0 = (unsigned)__shfl_xor((int)snd0, 32);
          unsigned r1 = (unsigned)__shfl_xor((int)snd1, 32);
          unsigned own0 = hi ? g10 : g00;
          unsigned own1 = hi ? g11 : g01;
          u32x4 wv;
          wv.x = hi ? r0 : own0;
          wv.y = hi ? r1 : own1;
          wv.z = hi ? own0 : r0;
          wv.w = hi ? own1 : r1;
          paf[f] = __builtin_bit_cast(bf16x8, wv);
        }
        // ---- PV ----
        __builtin_amdgcn_s_setprio(1);
#pragma unroll
        for (int n = 0; n < 4; n++) {
          o[n] = mfma32(paf[0], ldfrag(base + 4096 + (n * 2 + 0) * 512 + l * 8), o[n]);
          o[n] = mfma32(paf[1], ldfrag(base + 4096 + (n * 2 + 1) * 512 + l * 8), o[n]);
        }
        __builtin_amdgcn_s_setprio(0);
      }
      // no second barrier: triple buffer makes the restage safe
    }

    // ---- combine the two KV-half partials (in LDS; cold path, full syncs) ----
    __syncthreads();
    if (l < 32) {
      mlb[hw * 128 + grp * 64 + q31] = m;
      mlb[hw * 128 + grp * 64 + 32 + q31] = lsum;
    }
    __syncthreads();
    float m_o = mlb[hw * 128 + (grp ^ 1) * 64 + q31];
    float l_o = mlb[hw * 128 + (grp ^ 1) * 64 + 32 + q31];
    float M = fmaxf(m, m_o);
    float sc = exp2f(m - M);
    float lF = lsum * sc + l_o * exp2f(m_o - M);
#pragma unroll
    for (int rr = 0; rr < 16; rr++) {
      float sr = __shfl(sc, (rr & 3) + 8 * (rr >> 2) + 4 * hi);
      o[0][rr] *= sr; o[1][rr] *= sr; o[2][rr] *= sr; o[3][rr] *= sr;
    }
    float* ob = (float*)lds_raw + hw * 4096;   // [q32][d128] per head (staging dead now)
    if (grp == 1) {
#pragma unroll
      for (int rr = 0; rr < 16; rr++) {
        int cr = (rr & 3) + 8 * (rr >> 2) + 4 * hi;
#pragma unroll
        for (int n = 0; n < 4; n++) ob[cr * 128 + n * 32 + q31] = o[n][rr];
      }
    }
    __syncthreads();
    if (grp == 0) {
      float linv = 1.0f / lF;
#pragma unroll
      for (int rr = 0; rr < 16; rr++) {
        int cr = (rr & 3) + 8 * (rr >> 2) + 4 * hi;
        float lr = __shfl(linv, cr);
        int qrow = q0w + cr;
        size_t rowoff = ((size_t)(b * S_LEN + qrow)) * 2048 + hd * 128 + q31;
        Y[rowoff]      = f2bf((o[0][rr] + ob[cr * 128 + q31]) * lr);
        Y[rowoff + 32] = f2bf((o[1][rr] + ob[cr * 128 + 32 + q31]) * lr);
        Y[rowoff + 64] = f2bf((o[2][rr] + ob[cr * 128 + 64 + q31]) * lr);
        Y[rowoff + 96] = f2bf((o[3][rr] + ob[cr * 128 + 96 + q31]) * lr);
      }
    }
    __syncthreads();   // obuf consumed before next phase restages
  }
#undef STAGE1
}

// ---------------- launch ----------------
extern "C" void kernel_launch(void* const* d_in, const int* in_sizes, int n_in,
                              void* d_out, int out_size, void* d_ws, size_t ws_size,
                              hipStream_t stream) {
  const float* x  = (const float*)d_in[0];
  const float* rc = (const float*)d_in[1];
  const float* rs = (const float*)d_in[2];
  const float* Wq = (const float*)d_in[3];
  const float* Wk = (const float*)d_in[4];
  const float* Wv = (const float*)d_in[5];
  const float* Wo = (const float*)d_in[6];
  const float* qw = (const float*)d_in[7];
  const float* kw = (const float*)d_in[8];
  float* out = (float*)d_out;
  char* ws = (char*)d_ws;

  unsigned short* xb   = (unsigned short*)(ws + 0);          // live: prep + QKV GEMM
  unsigned short* WT   = (unsigned short*)(ws + 16777216);   // live: QKV GEMM
  unsigned short* WoT  = (unsigned short*)(ws + 29360128);   // live: until out GEMM
  unsigned short* Qpk  = (unsigned short*)(ws + 37748736);   // 16MB
  unsigned short* Kpk  = (unsigned short*)(ws + 54525952);   // 4MB
  unsigned short* Vpk  = (unsigned short*)(ws + 58720256);   // 4MB
  unsigned short* Yb   = (unsigned short*)(ws + 0);          // over xb (dead after QKV GEMM)

  prep_kernel<<<6656, 256, 0, stream>>>(x, Wq, Wk, Wv, Wo, xb, WT, WoT);
  // QKV GEMM (fused mid epilogue), 1D grid 768 = 24x32, XCD-swizzled.
  gemm_bf16_kernel<<<768, 256, 0, stream>>>(
      xb, WT, nullptr, 4096, 3072, 2048, 24, 1, rc, rs, qw, kw, Qpk, Kpk, Vpk);
  attn_kernel<<<256, 512, 0, stream>>>(Qpk, Kpk, Vpk, Yb);
  // out GEMM, 1D grid 512 = 16x32, XCD-swizzled.
  gemm_bf16_kernel<<<512, 256, 0, stream>>>(
      Yb, WoT, out, 4096, 2048, 2048, 16, 0, nullptr, nullptr, nullptr, nullptr,
      nullptr, nullptr, nullptr);
}